// Round 1
// 270.175 us; speedup vs baseline: 1.0729x; 1.0729x over previous
//
#include <hip/hip_runtime.h>
#include <hip/hip_bf16.h>

#define N_NODES 4096
#define BATCH   32
#define CIN     32
#define COUT    64
#define DEMB    16
#define NCOL    (BATCH * CIN)      // 1024 columns of the propagation GEMMs
#define KIO     (3 * CIN * COUT)   // 6144 generated-weight elements per node
#define SPLITK  2

typedef __bf16 bf16x8 __attribute__((ext_vector_type(8)));
typedef float  floatx4 __attribute__((ext_vector_type(4)));

__device__ inline void load_lds16(const void* g, void* l) {
    __builtin_amdgcn_global_load_lds(
        (const __attribute__((address_space(1))) void*)g,
        (__attribute__((address_space(3))) void*)l, 16, 0, 0);
}

// ---------------------------------------------------------------------------
// K0: U[n][m] = exp(relu(E[n].E[m])) (UNNORMALIZED, bf16) + invRow[n]=1/rowsum.
// softmax = diag(invRow) @ U; inv folded into GEMM combine epilogues.
// ---------------------------------------------------------------------------
__global__ __launch_bounds__(256) void compute_U_kernel(
        const float* __restrict__ E, __hip_bfloat16* __restrict__ U,
        float* __restrict__ invRow) {
    const int n0   = blockIdx.x * 8;
    const int t    = threadIdx.x;
    const int lane = t & 63, wave = t >> 6;
    __shared__ float red[4][8];

    float en[8][DEMB];
#pragma unroll
    for (int r = 0; r < 8; ++r) {
        const float4* er = (const float4*)&E[(size_t)(n0 + r) * DEMB];
        const float4 a0 = er[0], a1 = er[1], a2 = er[2], a3 = er[3];
        en[r][ 0]=a0.x; en[r][ 1]=a0.y; en[r][ 2]=a0.z; en[r][ 3]=a0.w;
        en[r][ 4]=a1.x; en[r][ 5]=a1.y; en[r][ 6]=a1.z; en[r][ 7]=a1.w;
        en[r][ 8]=a2.x; en[r][ 9]=a2.y; en[r][10]=a2.z; en[r][11]=a2.w;
        en[r][12]=a3.x; en[r][13]=a3.y; en[r][14]=a3.z; en[r][15]=a3.w;
    }

    float sum[8] = {0.f, 0.f, 0.f, 0.f, 0.f, 0.f, 0.f, 0.f};

    for (int tile = 0; tile < 16; ++tile) {
        const int c = tile * 256 + t;
        const float4* em4 = (const float4*)&E[(size_t)c * DEMB];
        const float4 b0 = em4[0], b1 = em4[1], b2 = em4[2], b3 = em4[3];
        float em[DEMB];
        em[ 0]=b0.x; em[ 1]=b0.y; em[ 2]=b0.z; em[ 3]=b0.w;
        em[ 4]=b1.x; em[ 5]=b1.y; em[ 6]=b1.z; em[ 7]=b1.w;
        em[ 8]=b2.x; em[ 9]=b2.y; em[10]=b2.z; em[11]=b2.w;
        em[12]=b3.x; em[13]=b3.y; em[14]=b3.z; em[15]=b3.w;
#pragma unroll
        for (int r = 0; r < 8; ++r) {
            float dt = 0.f;
#pragma unroll
            for (int d = 0; d < DEMB; ++d) dt += en[r][d] * em[d];
            const float ev = __expf(fmaxf(dt, 0.f));
            sum[r] += ev;
            U[(size_t)(n0 + r) * N_NODES + c] = __float2bfloat16(ev);
        }
    }
#pragma unroll
    for (int r = 0; r < 8; ++r)
#pragma unroll
        for (int off = 32; off > 0; off >>= 1) sum[r] += __shfl_xor(sum[r], off);
    if (lane == 0)
#pragma unroll
        for (int r = 0; r < 8; ++r) red[wave][r] = sum[r];
    __syncthreads();
    if (t < 8)
        invRow[n0 + t] = 1.0f / (red[0][t] + red[1][t] + red[2][t] + red[3][t]);
}

// ---------------------------------------------------------------------------
// K1: x[b][m][c] (fp32) -> Xt[m][b*32+c] (bf16) and Bt1[b*32+c][m] (bf16)
// ---------------------------------------------------------------------------
__global__ __launch_bounds__(256) void transpose_kernel(
        const float* __restrict__ x,
        __hip_bfloat16* __restrict__ Xt, __hip_bfloat16* __restrict__ Bt) {
    const int m0 = blockIdx.x * 64;
    const int b  = blockIdx.y;
    const int t  = threadIdx.x;
    __shared__ float tile[64][33];
    {
        const int ml = t >> 2, cg = (t & 3) * 8;
        const float* src = &x[((size_t)b * N_NODES + (m0 + ml)) * CIN + cg];
        const float4 r0 = *(const float4*)src;
        const float4 r1 = *(const float4*)(src + 4);
        tile[ml][cg+0] = r0.x; tile[ml][cg+1] = r0.y; tile[ml][cg+2] = r0.z; tile[ml][cg+3] = r0.w;
        tile[ml][cg+4] = r1.x; tile[ml][cg+5] = r1.y; tile[ml][cg+6] = r1.z; tile[ml][cg+7] = r1.w;
    }
    __syncthreads();
    {
        const int ml = t >> 2, cg = (t & 3) * 8;
        __hip_bfloat16* dst = &Xt[(size_t)(m0 + ml) * NCOL + b * CIN + cg];
#pragma unroll
        for (int j = 0; j < 8; ++j) dst[j] = __float2bfloat16(tile[ml][cg + j]);
    }
    {
        const int c = t >> 3, mg = (t & 7) * 8;
        __hip_bfloat16* dst = &Bt[(size_t)(b * CIN + c) * N_NODES + m0 + mg];
#pragma unroll
        for (int j = 0; j < 8; ++j) dst[j] = __float2bfloat16(tile[mg + j][c]);
    }
}

// ---------------------------------------------------------------------------
// K2 v4: generated weights into the SWIZZLED layout final_kernel reads:
//   dest[n][c*2048 + ot*512 + l16*32 + kk] = sum_d E[n][d]*Wp[d][(c*32+kk)*64+ot*16+l16]
// ---------------------------------------------------------------------------
__global__ __launch_bounds__(256) void gen_w_kernel(
        const float* __restrict__ E, const float* __restrict__ Wp,
        __hip_bfloat16* __restrict__ Wn) {
    const int c   = blockIdx.x >> 3;          // cheb index 0..2
    const int oo0 = (blockIdx.x & 7) * 8;     // output-col group base
    const int nc  = blockIdx.y * 64;          // node group
    const int t   = threadIdx.x;
    const int kk  = t & 31;                   // within-c row index 0..31
    const int oo  = oo0 + (t >> 5);           // output col 0..63

    __shared__ float et[64][DEMB];            // 4 KB: 64 E rows
    ((float4*)et)[t] = ((const float4*)&E[(size_t)nc * DEMB])[t];
    __syncthreads();

    const int srccol = (c * 32 + kk) * 64 + oo;
    float w[DEMB];
#pragma unroll
    for (int d = 0; d < DEMB; ++d) w[d] = Wp[(size_t)d * KIO + srccol];

    const int dstoff = c * 2048 + (oo >> 4) * 512 + (oo & 15) * 32 + kk;
    for (int nl = 0; nl < 64; ++nl) {
        float acc = 0.0f;
#pragma unroll
        for (int d = 0; d < DEMB; ++d) acc += et[nl][d] * w[d];
        Wn[(size_t)(nc + nl) * KIO + dstoff] = __float2bfloat16(acc);
    }
}

// ---------------------------------------------------------------------------
// K3 v2: deep-pipelined split-K GEMM (T2+T3+T4+T5).
//   BM=256, BN=128, BK=64, 512 threads (8 waves = 4x2, 64x64 per wave).
//   3 LDS buffers (144 KB, 1 block/CU), depth-2 K-tile prefetch.
//   2 phases per K-tile (one per ks); per phase: 8 ds_read_b128 -> issue half
//   of tile t+2's global_load_lds -> raw s_barrier -> setprio(1)+16 MFMA ->
//   raw s_barrier.  Counted s_waitcnt vmcnt(6) once per K-tile (after ph2
//   MFMA, before the tile-end barrier) validates tile t+1; never drains to 0
//   in the main loop.  Granule-XOR LDS swizzle kept from the 0-conflict
//   128^2 version.  SPLITK=2 -> grid 16x8x2 = 256 blocks = 1/CU.
// ---------------------------------------------------------------------------
#define GBM 256
#define GBN 128
#define GBK 64
#define NBUF 3

__global__ __launch_bounds__(512, 2) void gemm_splitk_kernel(
        const __hip_bfloat16* __restrict__ A,    // [M][K]
        const __hip_bfloat16* __restrict__ Bt,   // [NC][K]
        __hip_bfloat16* __restrict__ P,          // [SPLITK][M][NC] bf16 partials
        int M, int NC, int K) {
    const int t    = threadIdx.x;
    const int row0 = blockIdx.x * GBM;
    const int col0 = blockIdx.y * GBN;
    const int z    = blockIdx.z;
    const int NT   = (K >> 6) / SPLITK;        // 32 K-tiles of BK=64 per block
    const int kb0  = z * NT * GBK;

    __shared__ alignas(16) __hip_bfloat16 As[NBUF][GBM * GBK];  // 96 KB
    __shared__ alignas(16) __hip_bfloat16 Bs[NBUF][GBN * GBK];  // 48 KB

    const int lane = t & 63, wave = t >> 6;
    const int l16 = lane & 15, quad = lane >> 4;
    const int wr = wave >> 1, wc = wave & 1;
    const int wrow = wr * 64, wcol = wc * 64;
    const int xr = l16 & 7;

    auto stageA = [&](int buf, int kb, int s) {
        const int gi = s * 512 + t;            // 16B granule index
        const int r  = gi >> 3;                // tile row 0..255
        const int cg = (gi & 7) ^ (r & 7);     // swizzled global granule col
        load_lds16(&A[(size_t)(row0 + r) * K + kb + cg * 8], &As[buf][gi * 8]);
    };
    auto stageB = [&](int buf, int kb, int s) {
        const int gi = s * 512 + t;
        const int r  = gi >> 3;                // tile row 0..127
        const int cg = (gi & 7) ^ (r & 7);
        load_lds16(&Bt[(size_t)(col0 + r) * K + kb + cg * 8], &Bs[buf][gi * 8]);
    };

    floatx4 acc[4][4] = {};

    // ---- prologue: stage tiles 0 and 1, validate tile 0 (allow t1 in flight)
#pragma unroll
    for (int s = 0; s < 4; ++s) stageA(0, kb0, s);
#pragma unroll
    for (int s = 0; s < 2; ++s) stageB(0, kb0, s);
#pragma unroll
    for (int s = 0; s < 4; ++s) stageA(1, kb0 + GBK, s);
#pragma unroll
    for (int s = 0; s < 2; ++s) stageB(1, kb0 + GBK, s);
    asm volatile("s_waitcnt vmcnt(6)" ::: "memory");
    __builtin_amdgcn_s_barrier();
    __builtin_amdgcn_sched_barrier(0);

    int cur = 0;
    for (int tt = 0; tt < NT; ++tt) {
        const int  nb  = (cur + 2 >= NBUF) ? cur + 2 - NBUF : cur + 2;
        const int  kbn = kb0 + (tt + 2) * GBK;
        const bool pf  = (tt + 2 < NT);

        // ================= phase 1 : ks = 0 =================
        bf16x8 af0[4], bf0[4];
#pragma unroll
        for (int i = 0; i < 4; ++i)
            af0[i] = *(const bf16x8*)&As[cur][(wrow + i * 16 + l16) * GBK +
                                             ((quad ^ xr) * 8)];
#pragma unroll
        for (int j = 0; j < 4; ++j)
            bf0[j] = *(const bf16x8*)&Bs[cur][(wcol + j * 16 + l16) * GBK +
                                             ((quad ^ xr) * 8)];
        if (pf) { stageA(nb, kbn, 0); stageA(nb, kbn, 1); stageB(nb, kbn, 0); }
        __builtin_amdgcn_s_barrier();
        __builtin_amdgcn_s_setprio(1);
#pragma unroll
        for (int i = 0; i < 4; ++i)
#pragma unroll
            for (int j = 0; j < 4; ++j)
                acc[i][j] = __builtin_amdgcn_mfma_f32_16x16x32_bf16(
                                af0[i], bf0[j], acc[i][j], 0, 0, 0);
        __builtin_amdgcn_s_setprio(0);
        __builtin_amdgcn_s_barrier();

        // ================= phase 2 : ks = 1 =================
        bf16x8 af1[4], bf1[4];
#pragma unroll
        for (int i = 0; i < 4; ++i)
            af1[i] = *(const bf16x8*)&As[cur][(wrow + i * 16 + l16) * GBK +
                                             (((4 + quad) ^ xr) * 8)];
#pragma unroll
        for (int j = 0; j < 4; ++j)
            bf1[j] = *(const bf16x8*)&Bs[cur][(wcol + j * 16 + l16) * GBK +
                                             (((4 + quad) ^ xr) * 8)];
        if (pf) { stageA(nb, kbn, 2); stageA(nb, kbn, 3); stageB(nb, kbn, 1); }
        __builtin_amdgcn_s_barrier();
        __builtin_amdgcn_s_setprio(1);
#pragma unroll
        for (int i = 0; i < 4; ++i)
#pragma unroll
            for (int j = 0; j < 4; ++j)
                acc[i][j] = __builtin_amdgcn_mfma_f32_16x16x32_bf16(
                                af1[i], bf1[j], acc[i][j], 0, 0, 0);
        __builtin_amdgcn_s_setprio(0);
        // validate tile tt+1 for next iteration; keep tt+2's 6 loads in flight
        if (pf) asm volatile("s_waitcnt vmcnt(6)" ::: "memory");
        else    asm volatile("s_waitcnt vmcnt(0)" ::: "memory");
        __builtin_amdgcn_s_barrier();
        __builtin_amdgcn_sched_barrier(0);

        cur = (cur + 1 == NBUF) ? 0 : cur + 1;
    }

    __hip_bfloat16* Pz = P + (size_t)z * M * NC;
#pragma unroll
    for (int i = 0; i < 4; ++i)
#pragma unroll
        for (int j = 0; j < 4; ++j)
#pragma unroll
            for (int r = 0; r < 4; ++r) {
                const int rg = row0 + wrow + i * 16 + quad * 4 + r;
                const int cg = col0 + wcol + j * 16 + l16;
                Pz[(size_t)rg * NC + cg] = __float2bfloat16(acc[i][j][r]);
            }
}

// ---------------------------------------------------------------------------
// K3b: combine1 -> Y1 = bf16(inv[row] * sum_z Pz), plus transposed Y1t
// ---------------------------------------------------------------------------
__global__ __launch_bounds__(256) void combine1_kernel(
        const __hip_bfloat16* __restrict__ P, const float* __restrict__ invRow,
        __hip_bfloat16* __restrict__ Y, __hip_bfloat16* __restrict__ Yt,
        int M, int NC) {
    const int c0 = blockIdx.x * 64, m0 = blockIdx.y * 64;
    const int t = threadIdx.x;
    __shared__ float tile[64][65];
    const size_t stride = (size_t)M * NC;
#pragma unroll
    for (int j = 0; j < 16; ++j) {
        const int lin = t + j * 256;
        const int r = lin >> 6, c = lin & 63;
        const size_t idx = (size_t)(m0 + r) * NC + c0 + c;
        float s = 0.f;
#pragma unroll
        for (int z = 0; z < SPLITK; ++z) s += __bfloat162float(P[idx + z * stride]);
        s *= invRow[m0 + r];
        tile[r][c] = s;
        Y[idx] = __float2bfloat16(s);
    }
    __syncthreads();
#pragma unroll
    for (int j = 0; j < 16; ++j) {
        const int lin = t + j * 256;
        const int c = lin >> 6, r = lin & 63;
        Yt[(size_t)(c0 + c) * M + m0 + r] = __float2bfloat16(tile[r][c]);
    }
}

// ---------------------------------------------------------------------------
// K3c: combine2 -> Y2 = bf16(2*inv[row]*sum_z Pz - Xt)  (Chebyshev T2)
// ---------------------------------------------------------------------------
__global__ __launch_bounds__(256) void combine2_kernel(
        const __hip_bfloat16* __restrict__ P, const float* __restrict__ invRow,
        const __hip_bfloat16* __restrict__ sub, __hip_bfloat16* __restrict__ Y2,
        int M, int NC) {
    const size_t stride = (size_t)M * NC;
    const size_t idx0 = (size_t)blockIdx.x * 4096 + threadIdx.x;
#pragma unroll
    for (int j = 0; j < 16; ++j) {
        const size_t idx = idx0 + (size_t)j * 256;
        float s = 0.f;
#pragma unroll
        for (int z = 0; z < SPLITK; ++z) s += __bfloat162float(P[idx + z * stride]);
        s *= invRow[idx >> 10];          // row = idx / NCOL (NCOL = 1024)
        Y2[idx] = __float2bfloat16(2.0f * s - __bfloat162float(sub[idx]));
    }
}

// ---------------------------------------------------------------------------
// K4: per-node grouped GEMM via MFMA. out[b][n][o] = sum_k G[b][k] W[k][o] + bias
// ---------------------------------------------------------------------------
__global__ __launch_bounds__(256) void final_kernel(
        const __hip_bfloat16* __restrict__ Xt, const __hip_bfloat16* __restrict__ Y1,
        const __hip_bfloat16* __restrict__ Y2, const __hip_bfloat16* __restrict__ Wn,
        const float* __restrict__ E, const float* __restrict__ bias_pool,
        float* __restrict__ out) {
    const int t    = threadIdx.x;
    const int lane = t & 63, wave = t >> 6;
    const int l16  = lane & 15, quad = lane >> 4;
    const int n    = blockIdx.x * 4 + wave;

    const __hip_bfloat16* srcs[3] = {Xt, Y1, Y2};
    const __hip_bfloat16* Wnode = Wn + (size_t)n * KIO;   // [c][ot][l16][kk]

    floatx4 acc[2][4] = {};   // [mt][ot]

#pragma unroll
    for (int c = 0; c < 3; ++c) {
        bf16x8 af[2];
#pragma unroll
        for (int mt = 0; mt < 2; ++mt)
            af[mt] = *(const bf16x8*)&srcs[c][(size_t)n * NCOL +
                                              (mt * 16 + l16) * 32 + quad * 8];
#pragma unroll
        for (int ot = 0; ot < 4; ++ot) {
            const bf16x8 bfr = *(const bf16x8*)&Wnode[(size_t)c * 2048 +
                                                      ot * 512 + l16 * 32 + quad * 8];
#pragma unroll
            for (int mt = 0; mt < 2; ++mt)
                acc[mt][ot] = __builtin_amdgcn_mfma_f32_16x16x32_bf16(
                                  af[mt], bfr, acc[mt][ot], 0, 0, 0);
        }
    }

    float en[DEMB];
#pragma unroll
    for (int d = 0; d < DEMB; ++d) en[d] = E[(size_t)n * DEMB + d];
#pragma unroll
    for (int ot = 0; ot < 4; ++ot) {
        float bv = 0.f;
        const int o = ot * 16 + l16;
#pragma unroll
        for (int d = 0; d < DEMB; ++d) bv += en[d] * bias_pool[d * COUT + o];
#pragma unroll
        for (int mt = 0; mt < 2; ++mt)
#pragma unroll
            for (int r = 0; r < 4; ++r) {
                const int b = mt * 16 + quad * 4 + r;
                out[((size_t)b * N_NODES + n) * COUT + o] = acc[mt][ot][r] + bv;
            }
    }
}

// ---------------------------------------------------------------------------
extern "C" void kernel_launch(void* const* d_in, const int* in_sizes, int n_in,
                              void* d_out, int out_size, void* d_ws, size_t ws_size,
                              hipStream_t stream) {
    (void)in_sizes; (void)n_in; (void)out_size; (void)ws_size;
    const float* x  = (const float*)d_in[0];
    const float* E  = (const float*)d_in[1];
    // d_in[2] = laplacian_mx, unused by the reference forward
    const float* Wp = (const float*)d_in[3];
    const float* bp = (const float*)d_in[4];
    float* out = (float*)d_out;

    char* ws = (char*)d_ws;
    __hip_bfloat16* U   = (__hip_bfloat16*)(ws);                 // 33554432 B (unnormalized exp)
    __hip_bfloat16* Xt  = (__hip_bfloat16*)(ws + 33554432);      //  8388608 B
    __hip_bfloat16* Bt1 = (__hip_bfloat16*)(ws + 41943040);      //  8388608 B (X^T; reused as Y2)
    __hip_bfloat16* Y1  = (__hip_bfloat16*)(ws + 50331648);      //  8388608 B
    __hip_bfloat16* Y1t = (__hip_bfloat16*)(ws + 58720256);      //  8388608 B
    __hip_bfloat16* P   = (__hip_bfloat16*)(ws + 67108864);      // 16777216 B bf16 partials [2][4096][1024]
    float*       invRow = (float*)(ws + 67108864 + 25165824);    //    16384 B (dead before Wn written)
    __hip_bfloat16* Wn  = (__hip_bfloat16*)(ws + 67108864);      // 50331648 B (SAME region: P+invRow dead before gen_w)
    // total ws use: 117440512 B

    compute_U_kernel<<<N_NODES / 8, 256, 0, stream>>>(E, U, invRow);
    transpose_kernel<<<dim3(N_NODES / 64, BATCH), 256, 0, stream>>>(x, Xt, Bt1);
    // Y1 = inv * (U @ X) : grid x = row-strip (XCD-co-locates A-strip sharers)
    gemm_splitk_kernel<<<dim3(N_NODES / GBM, NCOL / GBN, SPLITK), 512, 0, stream>>>(
        U, Bt1, P, N_NODES, NCOL, N_NODES);
    combine1_kernel<<<dim3(NCOL / 64, N_NODES / 64), 256, 0, stream>>>(
        P, invRow, Y1, Y1t, N_NODES, NCOL);
    // Y2 = 2*inv*(U @ Y1) - X
    gemm_splitk_kernel<<<dim3(N_NODES / GBM, NCOL / GBN, SPLITK), 512, 0, stream>>>(
        U, Y1t, P, N_NODES, NCOL, N_NODES);
    combine2_kernel<<<dim3(N_NODES * NCOL / 4096), 256, 0, stream>>>(
        P, invRow, Xt, Bt1, N_NODES, NCOL);
    // gen_w AFTER combine2: Wn shares the P/invRow region
    gen_w_kernel<<<dim3(24, N_NODES / 64), 256, 0, stream>>>(E, Wp, Wn);
    final_kernel<<<N_NODES / 4, 256, 0, stream>>>(Xt, Y1, Bt1, Wn, E, bp, out);
}